// Round 1
// baseline (333.032 us; speedup 1.0000x reference)
//
#include <hip/hip_runtime.h>
#include <hip/hip_bf16.h>
#include <stdint.h>

#define TOKENS 4096
#define IN_F   4096
#define OUT_F  4096
#define NNZ    512

using floatx4 = __attribute__((ext_vector_type(4))) float;
using bf16x8  = __attribute__((ext_vector_type(8))) __bf16;

__device__ __forceinline__ unsigned short f2bf(float f) {
    unsigned int u = __float_as_uint(f);
    u += 0x7FFFu + ((u >> 16) & 1u);   // round-to-nearest-even
    return (unsigned short)(u >> 16);
}

// Kernel 1: convert x (fp32) -> Xb (bf16), and zero dense W buffer.
// One uint4 (8 bf16) per thread for both arrays; 8192 blocks x 256.
__global__ void prep_convert_zero(const float* __restrict__ x,
                                  unsigned short* __restrict__ Xb,
                                  unsigned short* __restrict__ Wb) {
    int i = blockIdx.x * 256 + threadIdx.x;
    const float4* xv = (const float4*)x;
    float4 a = xv[2 * i];
    float4 b = xv[2 * i + 1];
    uint4 o;
    o.x = (unsigned)f2bf(a.x) | ((unsigned)f2bf(a.y) << 16);
    o.y = (unsigned)f2bf(a.z) | ((unsigned)f2bf(a.w) << 16);
    o.z = (unsigned)f2bf(b.x) | ((unsigned)f2bf(b.y) << 16);
    o.w = (unsigned)f2bf(b.z) | ((unsigned)f2bf(b.w) << 16);
    ((uint4*)Xb)[i] = o;
    ((uint4*)Wb)[i] = make_uint4(0u, 0u, 0u, 0u);
}

// Kernel 2: scatter condensed weights into dense bf16 W [OUT_F][IN_F].
// mask rows are sorted, so duplicate indices are adjacent: the first thread
// of each run sums the run in fp32 and does a single non-atomic store.
__global__ void scatter_w(const float* __restrict__ w,
                          const int* __restrict__ mask,
                          unsigned short* __restrict__ Wb) {
    int gid = blockIdx.x * 256 + threadIdx.x;   // o*512 + k
    int o = gid >> 9;
    int k = gid & (NNZ - 1);
    int idx = mask[gid];
    if (k > 0 && mask[gid - 1] == idx) return;  // not run leader
    float s = w[gid];
    int j = gid + 1;
    int kend = (o << 9) + NNZ;
    while (j < kend && mask[j] == idx) { s += w[j]; ++j; }
    Wb[(size_t)o * IN_F + idx] = f2bf(s);
}

// Kernel 3: C[m][n] = sum_k A[m][k] * B[n][k] + bias[n]
// A = Xb bf16 [4096][4096], B = Wb bf16 [4096][4096] (i.e. B^T layout).
// m97 recipe: 128x128 block tile, 4 waves in 2x2 (64x64 each), 4x4 grid of
// 16x16x32 bf16 MFMA per wave, BK=64, global_load_lds width=16 staging.
__global__ __launch_bounds__(256) void gemm_bt_bias(
        const unsigned short* __restrict__ A,
        const unsigned short* __restrict__ B,
        const float* __restrict__ bias,
        float* __restrict__ C) {
    __shared__ unsigned short As[128 * 64];
    __shared__ unsigned short Bs[128 * 64];

    const int tid  = threadIdx.x;
    const int wave = tid >> 6;
    const int lane = tid & 63;
    const int m0 = blockIdx.y * 128;
    const int n0 = blockIdx.x * 128;
    const int wm = (wave >> 1) * 64;   // wave row offset in tile
    const int wn = (wave & 1) * 64;    // wave col offset in tile

    floatx4 acc[4][4] = {};

    // staging decomposition: tile = 1024 chunks of 16B (8 bf16).
    // chunk c = (i*4 + wave)*64 + lane ; row = c>>3 ; kseg = c&7.
    // LDS dest = wave-uniform base + lane*16 (global_load_lds semantics).
    const int lrow = lane >> 3;
    const int kseg = lane & 7;
    const int lq   = lane >> 4;        // quad 0..3
    const int lm   = lane & 15;

    for (int k0 = 0; k0 < IN_F; k0 += 64) {
#pragma unroll
        for (int i = 0; i < 4; ++i) {
            const int cb  = (i * 4 + wave);
            const int row = cb * 8 + lrow;
            const unsigned short* ga =
                A + (size_t)(m0 + row) * IN_F + k0 + kseg * 8;
            const unsigned short* gb =
                B + (size_t)(n0 + row) * IN_F + k0 + kseg * 8;
            __builtin_amdgcn_global_load_lds(
                (__attribute__((address_space(1))) void*)ga,
                (__attribute__((address_space(3))) void*)(As + cb * 512),
                16, 0, 0);
            __builtin_amdgcn_global_load_lds(
                (__attribute__((address_space(1))) void*)gb,
                (__attribute__((address_space(3))) void*)(Bs + cb * 512),
                16, 0, 0);
        }
        __syncthreads();   // drains vmcnt before barrier -> staging complete

#pragma unroll
        for (int ks = 0; ks < 2; ++ks) {
            const int kb = ks * 32 + lq * 8;
            bf16x8 af[4], bfr[4];
#pragma unroll
            for (int mi = 0; mi < 4; ++mi)
                af[mi] = *(const bf16x8*)(As + (wm + mi * 16 + lm) * 64 + kb);
#pragma unroll
            for (int ni = 0; ni < 4; ++ni)
                bfr[ni] = *(const bf16x8*)(Bs + (wn + ni * 16 + lm) * 64 + kb);
#pragma unroll
            for (int mi = 0; mi < 4; ++mi)
#pragma unroll
                for (int ni = 0; ni < 4; ++ni)
                    acc[mi][ni] = __builtin_amdgcn_mfma_f32_16x16x32_bf16(
                        af[mi], bfr[ni], acc[mi][ni], 0, 0, 0);
        }
        __syncthreads();   // protect LDS before next stage
    }

    // Epilogue: C/D layout col = lane&15, row = (lane>>4)*4 + reg  [m89]
#pragma unroll
    for (int ni = 0; ni < 4; ++ni) {
        const int n = n0 + wn + ni * 16 + lm;
        const float bv = bias[n];
#pragma unroll
        for (int mi = 0; mi < 4; ++mi) {
            const int mbase = m0 + wm + mi * 16 + lq * 4;
#pragma unroll
            for (int r = 0; r < 4; ++r) {
                C[(size_t)(mbase + r) * OUT_F + n] = acc[mi][ni][r] + bv;
            }
        }
    }
}

extern "C" void kernel_launch(void* const* d_in, const int* in_sizes, int n_in,
                              void* d_out, int out_size, void* d_ws, size_t ws_size,
                              hipStream_t stream) {
    const float* x    = (const float*)d_in[0];   // [4096,4096] fp32
    const float* w    = (const float*)d_in[1];   // [4096,512]  fp32
    const int*   mask = (const int*)d_in[2];     // [4096,512]  int32 (sorted rows)
    const float* bias = (const float*)d_in[3];   // [4096]      fp32
    float* out = (float*)d_out;                  // [4096,4096] fp32

    // Workspace: Xb bf16 (32 MiB) | Wb bf16 (32 MiB) = 64 MiB total.
    unsigned short* Xb = (unsigned short*)d_ws;
    unsigned short* Wb = Xb + (size_t)TOKENS * IN_F;

    prep_convert_zero<<<8192, 256, 0, stream>>>(x, Xb, Wb);
    scatter_w<<<8192, 256, 0, stream>>>(w, mask, Wb);
    dim3 grid(32, 32);
    gemm_bt_bias<<<grid, 256, 0, stream>>>(Xb, Wb, bias, out);
}

// Round 2
// 282.027 us; speedup vs baseline: 1.1809x; 1.1809x over previous
//
#include <hip/hip_runtime.h>
#include <hip/hip_bf16.h>
#include <stdint.h>

#define TOKENS 4096
#define IN_F   4096
#define OUT_F  4096
#define NNZ    512

using floatx4 = __attribute__((ext_vector_type(4))) float;
using bf16x8  = __attribute__((ext_vector_type(8))) __bf16;

__device__ __forceinline__ unsigned short f2bf(float f) {
    unsigned int u = __float_as_uint(f);
    u += 0x7FFFu + ((u >> 16) & 1u);   // round-to-nearest-even
    return (unsigned short)(u >> 16);
}

// Fused prep:
//  blocks [0, 4096)       : build dense bf16 W row in LDS (zero + run-leader
//                           scatter), then one coalesced row store. No
//                           scattered global stores, no separate zero pass.
//  blocks [4096, 12288)   : convert x fp32 -> bf16, 8 elems/thread.
__global__ __launch_bounds__(256) void prep_fused(
        const float* __restrict__ x,
        const float* __restrict__ w,
        const int*   __restrict__ mask,
        unsigned short* __restrict__ Xb,
        unsigned short* __restrict__ Wb) {
    __shared__ unsigned short row[IN_F];   // 8 KB
    const int b = blockIdx.x;
    const int t = threadIdx.x;

    if (b < OUT_F) {
        // zero the LDS row: 4096 shorts = 512 uint4; 2 per thread
        uint4* rv = (uint4*)row;
        rv[t]       = make_uint4(0u, 0u, 0u, 0u);
        rv[t + 256] = make_uint4(0u, 0u, 0u, 0u);
        __syncthreads();

        const int base = b * NNZ;
#pragma unroll
        for (int e = 0; e < 2; ++e) {
            const int k = t + e * 256;
            const int idx = mask[base + k];
            // run leader: first occurrence of idx in this sorted row
            if (k == 0 || mask[base + k - 1] != idx) {
                float s = w[base + k];
                int j = k + 1;
                while (j < NNZ && mask[base + j] == idx) { s += w[base + j]; ++j; }
                row[idx] = f2bf(s);
            }
        }
        __syncthreads();

        uint4* out = (uint4*)(Wb + (size_t)b * IN_F);
        out[t]       = rv[t];
        out[t + 256] = rv[t + 256];
    } else {
        const int i = (b - OUT_F) * 256 + t;
        const float4* xv = (const float4*)x;
        float4 a = xv[2 * i];
        float4 c = xv[2 * i + 1];
        uint4 o;
        o.x = (unsigned)f2bf(a.x) | ((unsigned)f2bf(a.y) << 16);
        o.y = (unsigned)f2bf(a.z) | ((unsigned)f2bf(a.w) << 16);
        o.z = (unsigned)f2bf(c.x) | ((unsigned)f2bf(c.y) << 16);
        o.w = (unsigned)f2bf(c.z) | ((unsigned)f2bf(c.w) << 16);
        ((uint4*)Xb)[i] = o;
    }
}

// GEMM: C[m][n] = sum_k A[m][k] * B[n][k] + bias[n]
// 128x128 tile, 4 waves 2x2, 4x4 of 16x16x32 bf16 MFMA per wave, BK=64,
// global_load_lds width=16 staging.
//
// LDS bank-conflict fix (R1): rows are 64 bf16 = 128 B = 32 banks, so all
// lanes of a quad reading the same k-chunk of different rows 16-way
// conflict. XOR swizzle: LDS slot (r, s) holds global chunk (r, s ^ (r&7)).
// global_load_lds pins the LDS dest to base+lane*16, so the swizzle is done
// by permuting the SOURCE seg each lane loads (stays within the row's 128 B
// line -> coalescing preserved). Reads use chunk (cs ^ (lm&7)) -> 16 lanes
// spread over 8 bank groups = 2-way conflict = free (m136).
__global__ __launch_bounds__(256) void gemm_bt_bias(
        const unsigned short* __restrict__ A,
        const unsigned short* __restrict__ B,
        const float* __restrict__ bias,
        float* __restrict__ C) {
    __shared__ unsigned short As[128 * 64];
    __shared__ unsigned short Bs[128 * 64];

    const int tid  = threadIdx.x;
    const int wave = tid >> 6;
    const int lane = tid & 63;
    const int m0 = blockIdx.y * 128;
    const int n0 = blockIdx.x * 128;
    const int wm = (wave >> 1) * 64;
    const int wn = (wave & 1) * 64;

    floatx4 acc[4][4] = {};

    const int lrow = lane >> 3;                  // r & 7 for this lane's chunk
    const int kseg = (lane & 7) ^ lrow;          // swizzled source seg
    const int lq   = lane >> 4;
    const int lm   = lane & 15;
    const int lm7  = lm & 7;

    for (int k0 = 0; k0 < IN_F; k0 += 64) {
#pragma unroll
        for (int i = 0; i < 4; ++i) {
            const int cb  = (i * 4 + wave);
            const int row = cb * 8 + lrow;
            const unsigned short* ga =
                A + (size_t)(m0 + row) * IN_F + k0 + kseg * 8;
            const unsigned short* gb =
                B + (size_t)(n0 + row) * IN_F + k0 + kseg * 8;
            __builtin_amdgcn_global_load_lds(
                (__attribute__((address_space(1))) void*)ga,
                (__attribute__((address_space(3))) void*)(As + cb * 512),
                16, 0, 0);
            __builtin_amdgcn_global_load_lds(
                (__attribute__((address_space(1))) void*)gb,
                (__attribute__((address_space(3))) void*)(Bs + cb * 512),
                16, 0, 0);
        }
        __syncthreads();

#pragma unroll
        for (int ks = 0; ks < 2; ++ks) {
            bf16x8 af[4], bfr[4];
#pragma unroll
            for (int mi = 0; mi < 4; ++mi) {
                const int chunk = (ks * 4 + lq) ^ lm7;
                af[mi] = *(const bf16x8*)(As + (wm + mi * 16 + lm) * 64 + chunk * 8);
            }
#pragma unroll
            for (int ni = 0; ni < 4; ++ni) {
                const int chunk = (ks * 4 + lq) ^ lm7;
                bfr[ni] = *(const bf16x8*)(Bs + (wn + ni * 16 + lm) * 64 + chunk * 8);
            }
#pragma unroll
            for (int mi = 0; mi < 4; ++mi)
#pragma unroll
                for (int ni = 0; ni < 4; ++ni)
                    acc[mi][ni] = __builtin_amdgcn_mfma_f32_16x16x32_bf16(
                        af[mi], bfr[ni], acc[mi][ni], 0, 0, 0);
        }
        __syncthreads();
    }

    // Epilogue: C/D layout col = lane&15, row = (lane>>4)*4 + reg  [m89]
#pragma unroll
    for (int ni = 0; ni < 4; ++ni) {
        const int n = n0 + wn + ni * 16 + lm;
        const float bv = bias[n];
#pragma unroll
        for (int mi = 0; mi < 4; ++mi) {
            const int mbase = m0 + wm + mi * 16 + lq * 4;
#pragma unroll
            for (int r = 0; r < 4; ++r) {
                C[(size_t)(mbase + r) * OUT_F + n] = acc[mi][ni][r] + bv;
            }
        }
    }
}

extern "C" void kernel_launch(void* const* d_in, const int* in_sizes, int n_in,
                              void* d_out, int out_size, void* d_ws, size_t ws_size,
                              hipStream_t stream) {
    const float* x    = (const float*)d_in[0];   // [4096,4096] fp32
    const float* w    = (const float*)d_in[1];   // [4096,512]  fp32
    const int*   mask = (const int*)d_in[2];     // [4096,512]  int32 (sorted rows)
    const float* bias = (const float*)d_in[3];   // [4096]      fp32
    float* out = (float*)d_out;                  // [4096,4096] fp32

    unsigned short* Xb = (unsigned short*)d_ws;                 // 32 MiB
    unsigned short* Wb = Xb + (size_t)TOKENS * IN_F;            // 32 MiB

    prep_fused<<<OUT_F + 8192, 256, 0, stream>>>(x, w, mask, Xb, Wb);
    dim3 grid(32, 32);
    gemm_bt_bias<<<grid, 256, 0, stream>>>(Xb, Wb, bias, out);
}